// Round 12
// baseline (1186.376 us; speedup 1.0000x reference)
//
#include <hip/hip_runtime.h>
#include <stdint.h>
#include <stddef.h>

// ---------------------------------------------------------------------------
// InternLM2 attention block, fused pipeline:
//   f2bf(x,Wqkv,Wo) -> GEMM1(bf16)->QKV -> RoPE split -> V-transpose
//   -> flash attention (causal GQA) -> GEMM3(bf16, fp32 out)
// GEMMs: C = A * B^T with A(M,K), B(N,K) row-major.
// MFMA: v_mfma_f32_16x16x32_bf16. C/D: col=l&15, row=(l>>4)*4+j.
//
// R1: attn LDS XOR-swizzle (both-sides) -> attn 874 -> ~230 us.
// R2: same swizzle on GEMM LDS: conflicts 1.51e8 -> 0, GEMM1 681 -> 500 us.
// R3: 256^2 8-phase GEMM (m201 template): 918 TF, MfmaUtil 40%.
// R4/R7: fetch-reducing mappings: dur worse/null -> GEMM not fetch-paced.
// R5/R6: cross-phase read-ahead: spill (252/256 regs). Structurally closed.
// R8: manual lgkm waits removal: NULL.
// R9: 2 phases/K-tile (4 barriers): 396 us, 1041 TF, MfmaUtil 46%. GEMM
//     locked here: MFMA+LDS pipes sum to ~93% of cycles; further overlap
//     needs regs we don't have (m201's SGPR-addressing asm trick).
// R11: attn B-frag amortization: 32 q-rows/wave (QBLK=128, 4 waves).
//     Each kfr/vfr LDS fragment feeds 2 MFMAs (was 1): LDS reads/work -47%.
//     KV-tile loads per (b,h): 528 -> 272 (flash IO halves). Ps -> 16KB,
//     VGPR ~190 -> 2 blocks/CU. GEMMs byte-identical (control).
// ---------------------------------------------------------------------------

typedef unsigned short u16;
typedef __attribute__((ext_vector_type(8))) short short8;   // bf16x8 frag
typedef __attribute__((ext_vector_type(4))) float f32x4;    // MFMA acc
typedef __attribute__((ext_vector_type(4))) unsigned short u16x4;

typedef const __attribute__((address_space(1))) void* as1_cvp;
typedef __attribute__((address_space(3))) void* as3_vp;

__device__ __forceinline__ float bf2f(u16 u) {
  union { unsigned int i; float f; } v; v.i = ((unsigned)u) << 16; return v.f;
}
__device__ __forceinline__ u16 f2bf(float f) {
  union { float f; unsigned int i; } v; v.f = f;
  unsigned r = v.i + 0x7FFFu + ((v.i >> 16) & 1u);   // RNE
  return (u16)(r >> 16);
}
__device__ __forceinline__ void gload_lds16(const void* g, void* l) {
  __builtin_amdgcn_global_load_lds((as1_cvp)g, (as3_vp)l, 16, 0, 0);
}

// ---------------- fp32 -> bf16 convert (vectorized) ------------------------
__global__ __launch_bounds__(256) void k_f2bf(const float* __restrict__ in,
                                              u16* __restrict__ out) {
  size_t i = ((size_t)blockIdx.x * 256 + threadIdx.x) * 4;
  f32x4 v = *(const f32x4*)(in + i);
  u16x4 o;
  o[0] = f2bf(v[0]); o[1] = f2bf(v[1]); o[2] = f2bf(v[2]); o[3] = f2bf(v[3]);
  *(u16x4*)(out + i) = o;
}

// ---------------- 256x256 2-phase GEMM  C = A * B^T  (R9, locked) ----------
__device__ __forceinline__ void stage_region(const u16* __restrict__ G,
                                             int K, int kt,
                                             u16 (* __restrict__ XS)[64],
                                             int rmap, int w, int lane) {
  #pragma unroll
  for (int L = 0; L < 2; ++L) {
    const int g = w * 2 + L;
    int rb;
    if (rmap == 0)      rb = g * 8 + (g >> 3) * 64;            // A_lo
    else if (rmap == 1) rb = 64 + g * 8 + (g >> 3) * 64;       // A_hi
    else if (rmap == 2) rb = (g >> 2) * 64 + (g & 3) * 8;      // B_lo
    else                rb = 32 + (g >> 2) * 64 + (g & 3) * 8; // B_hi
    const int srow = rb + (lane >> 3);
    const int schunk = ((lane & 7) ^ ((lane >> 3) & 7)) * 8;
    gload_lds16(G + (size_t)srow * K + (size_t)kt * 64 + schunk, &XS[rb][0]);
  }
}

#define LDFRAG(XS, row, ks) \
  (*(const short8*)&XS[row][(((ks) * 32) + lhi * 8) ^ swz])

#define MFMA_Q(af, bf, mb, nb)                                              \
  _Pragma("unroll") for (int mf = 0; mf < 4; ++mf)                          \
  _Pragma("unroll") for (int nf = 0; nf < 2; ++nf)                          \
  _Pragma("unroll") for (int ks = 0; ks < 2; ++ks)                          \
    acc[(mb) + mf][(nb) + nf] = __builtin_amdgcn_mfma_f32_16x16x32_bf16(    \
        af[mf][ks], bf[nf][ks], acc[(mb) + mf][(nb) + nf], 0, 0, 0);

#define GEMM_HALF(H) {                                                      \
  const int tAhi  = (t + 1 + (H) < nkt) ? (t + 1 + (H)) : (nkt - 1);        \
  const int tNext = (t + 2 + (H) < nkt) ? (t + 2 + (H)) : (nkt - 1);        \
  short8 a0[4][2], a1[4][2], b0[2][2], b1[2][2];                            \
  /* ph1: 16 ds_reads; stage A_hi -> other buf; MFMA a0 x (b0,b1) */        \
  _Pragma("unroll") for (int mf = 0; mf < 4; ++mf) {                        \
    a0[mf][0] = LDFRAG(As[H], wm * 128 + mf * 16 + l16, 0);                 \
    a0[mf][1] = LDFRAG(As[H], wm * 128 + mf * 16 + l16, 1); }               \
  _Pragma("unroll") for (int nf = 0; nf < 2; ++nf) {                        \
    b0[nf][0] = LDFRAG(Bs[H], wn * 64 + nf * 16 + l16, 0);                  \
    b0[nf][1] = LDFRAG(Bs[H], wn * 64 + nf * 16 + l16, 1);                  \
    b1[nf][0] = LDFRAG(Bs[H], wn * 64 + (nf + 2) * 16 + l16, 0);            \
    b1[nf][1] = LDFRAG(Bs[H], wn * 64 + (nf + 2) * 16 + l16, 1); }          \
  stage_region(Ap, K, tAhi, As[1 - (H)], 1, w, lane);                       \
  __builtin_amdgcn_s_barrier();                                             \
  __builtin_amdgcn_s_setprio(1);                                            \
  MFMA_Q(a0, b0, 0, 0);                                                     \
  MFMA_Q(a0, b1, 0, 2);                                                     \
  __builtin_amdgcn_s_setprio(0);                                            \
  __builtin_amdgcn_s_barrier();                                             \
  /* ph2: 8 ds_reads (A_hi frags); stage A_lo,B_lo,B_hi; counted vmcnt */   \
  _Pragma("unroll") for (int mf = 0; mf < 4; ++mf) {                        \
    a1[mf][0] = LDFRAG(As[H], wm * 128 + (mf + 4) * 16 + l16, 0);           \
    a1[mf][1] = LDFRAG(As[H], wm * 128 + (mf + 4) * 16 + l16, 1); }         \
  stage_region(Ap, K, tNext, As[H], 0, w, lane);                            \
  stage_region(Bp, K, tNext, Bs[H], 2, w, lane);                            \
  stage_region(Bp, K, tNext, Bs[H], 3, w, lane);                            \
  asm volatile("s_waitcnt vmcnt(6)" ::: "memory");                          \
  __builtin_amdgcn_s_barrier();                                             \
  __builtin_amdgcn_s_setprio(1);                                            \
  MFMA_Q(a1, b0, 4, 0);                                                     \
  MFMA_Q(a1, b1, 4, 2);                                                     \
  __builtin_amdgcn_s_setprio(0);                                            \
  __builtin_amdgcn_s_barrier();                                             \
}

template<int WRITE_BF16>
__global__ __launch_bounds__(512, 2) void k_gemm256(const u16* __restrict__ A,
                                                    const u16* __restrict__ B,
                                                    void* __restrict__ Cout,
                                                    int M, int N, int K) {
  __shared__ u16 As[2][256][64];   // 64 KB
  __shared__ u16 Bs[2][256][64];   // 64 KB
  (void)M;
  const int tid  = threadIdx.x;
  const int lane = tid & 63;
  const int w    = tid >> 6;       // 0..7
  const int wm   = w >> 2;         // 0..1  (row half)
  const int wn   = w & 3;          // 0..3  (col quarter)
  const int l16  = lane & 15, lhi = lane >> 4;
  const int swz  = (l16 & 7) << 3;

  // R3 XCD swizzle (empirically best of 3 mappings; nwg % 8 == 0)
  const int nbx = gridDim.x;
  int id = blockIdx.y * nbx + blockIdx.x;
  const int cpx = (nbx * gridDim.y) >> 3;
  id = (id & 7) * cpx + (id >> 3);
  const long m0 = (long)(id / nbx) * 256;
  const long n0 = (long)(id % nbx) * 256;

  const u16* Ap = A + (size_t)m0 * K;
  const u16* Bp = B + (size_t)n0 * K;

  f32x4 acc[8][4] = {};
  const int nkt = K >> 6;
  const int niter = nkt >> 1;

  // prologue: tile0 (4 regions) -> buf0; tile1 (A_lo,B_lo,B_hi) -> buf1
  stage_region(Ap, K, 0, As[0], 0, w, lane);
  stage_region(Ap, K, 0, As[0], 1, w, lane);
  stage_region(Bp, K, 0, Bs[0], 2, w, lane);
  stage_region(Bp, K, 0, Bs[0], 3, w, lane);
  stage_region(Ap, K, 1, As[1], 0, w, lane);
  stage_region(Bp, K, 1, Bs[1], 2, w, lane);
  stage_region(Bp, K, 1, Bs[1], 3, w, lane);
  asm volatile("s_waitcnt vmcnt(6)" ::: "memory");   // tile0's 8 ops land
  __builtin_amdgcn_s_barrier();

  for (int i = 0; i < niter; ++i) {
    const int t = 2 * i;
    GEMM_HALF(0)
    GEMM_HALF(1)
  }

  asm volatile("s_waitcnt vmcnt(0)" ::: "memory");   // drain dummy prefetches
  #pragma unroll
  for (int mf = 0; mf < 8; ++mf)
    #pragma unroll
    for (int nf = 0; nf < 4; ++nf)
      #pragma unroll
      for (int j = 0; j < 4; ++j) {
        const size_t row = m0 + wm * 128 + mf * 16 + lhi * 4 + j;
        const size_t col = n0 + wn * 64 + nf * 16 + l16;
        const float v = acc[mf][nf][j];
        if (WRITE_BF16) ((u16*)Cout)[row * N + col] = f2bf(v);
        else            ((float*)Cout)[row * N + col] = v;
      }
}

// ---------------- RoPE + Q/K split -----------------------------------------
__global__ __launch_bounds__(256) void k_rope(const u16* __restrict__ QKV,
                                              u16* __restrict__ Qo,
                                              u16* __restrict__ Ko) {
  const unsigned tid = blockIdx.x * 256 + threadIdx.x;
  const int j    = tid & 63;
  const int slot = (tid >> 6) & 7;
  const int kvh  = (tid >> 9) & 7;
  const int t    = tid >> 12;            // 0..4095
  if (slot == 7) return;
  const int b = t >> 11, s = t & 2047;
  const size_t base = (size_t)t * 8192 + kvh * 1024 + slot * 128;
  const float v0 = bf2f(QKV[base + j]);
  const float v1 = bf2f(QKV[base + j + 64]);
  const float invf = __expf(-(float)j * 0.21586735246819181f);
  const float ang = (float)s * invf;
  float sn, cs;
  __sincosf(ang, &sn, &cs);
  const float o0 = v0 * cs - v1 * sn;
  const float o1 = v1 * cs + v0 * sn;
  if (slot < 6) {
    const int hh = kvh * 6 + slot;
    const size_t o = ((size_t)(b * 48 + hh) * 2048 + s) * 128 + j;
    Qo[o] = f2bf(o0); Qo[o + 64] = f2bf(o1);
  } else {
    const size_t o = ((size_t)(b * 8 + kvh) * 2048 + s) * 128 + j;
    Ko[o] = f2bf(o0); Ko[o + 64] = f2bf(o1);
  }
}

// ---------------- V transpose: QKV slot7 -> VT (B,KVH,D,S) -----------------
__global__ __launch_bounds__(256) void k_vtrans(const u16* __restrict__ QKV,
                                                u16* __restrict__ VT) {
  __shared__ u16 T[64][136];             // +8 pad
  const int bid = blockIdx.x;            // 2*8*32 = 512
  const int st  = bid & 31;
  const int kvh = (bid >> 5) & 7;
  const int b   = bid >> 8;
  const int tid = threadIdx.x;
  const int r   = tid >> 4;
  const int c8  = (tid & 15) * 8;
  const size_t qoff = ((size_t)(b * 2048 + st * 64)) * 8192 + kvh * 1024 + 896;
  #pragma unroll
  for (int p = 0; p < 4; ++p) {
    short8 v = *(const short8*)&QKV[qoff + (size_t)(p * 16 + r) * 8192 + c8];
    *(short8*)&T[p * 16 + r][c8] = v;
  }
  __syncthreads();
  const int dd = tid >> 3;
  const int s8 = (tid & 7) * 8;
  const size_t vbase = ((size_t)(b * 8 + kvh) * 128) * 2048 + st * 64;
  #pragma unroll
  for (int p = 0; p < 4; ++p) {
    const int d = p * 32 + dd;
    short8 o;
    #pragma unroll
    for (int i = 0; i < 8; ++i) o[i] = (short)T[s8 + i][d];
    *(short8*)&VT[vbase + (size_t)d * 2048 + s8] = o;
  }
}

// ---------------- flash attention (causal, GQA) ----------------------------
// R11: QBLK=128, 4 waves, 32 q-rows per wave (q2 in {0,1} selects the 16-row
// sub-block). Each kfr/vfr LDS fragment feeds 2 MFMAs. KVBLK=64 unchanged.
// Causal: kt in [0, 2*qt+1]; mask only when kt >= 2*qt.
__global__ __launch_bounds__(256) void k_attn(const u16* __restrict__ Q,
                                              const u16* __restrict__ Kg,
                                              const u16* __restrict__ VT,
                                              u16* __restrict__ CTX) {
  __shared__ u16 Ks[64][128];            // 16 KB (s-major, swizzled)
  __shared__ u16 Vs[128][64];            // 16 KB (d-major = V^T tile, swizzled)
  __shared__ u16 Ps[4][32][64];          // 16 KB, per-wave P (swizzled)
  const int bid = blockIdx.x;
  const int qt  = 15 - (bid / 96);       // LPT order, 16 q-tiles of 128 rows
  const int bh  = bid % 96;
  const int h   = bh % 48;
  const int b   = bh / 48;
  const int kvh = h / 6;
  const int tid = threadIdx.x, lane = tid & 63, w = tid >> 6;
  const int l16 = lane & 15, lhi = lane >> 4;
  const int swz = (l16 & 7) << 3;
  const float SC = 0.08838834764831845f; // 1/sqrt(128)

  short8 qf[2][4];
  #pragma unroll
  for (int q2 = 0; q2 < 2; ++q2) {
    const size_t qrow =
        ((size_t)(b * 48 + h) * 2048 + qt * 128 + w * 32 + q2 * 16 + l16) * 128;
    #pragma unroll
    for (int kc = 0; kc < 4; ++kc)
      qf[q2][kc] = *(const short8*)&Q[qrow + kc * 32 + lhi * 8];
  }
  f32x4 cacc[2][8] = {};
  float m_r[2][4], l_r[2][4];
  #pragma unroll
  for (int q2 = 0; q2 < 2; ++q2)
    #pragma unroll
    for (int j = 0; j < 4; ++j) { m_r[q2][j] = -1e30f; l_r[q2][j] = 0.f; }

  const u16* Kb = Kg + (size_t)(b * 8 + kvh) * 2048 * 128;
  const u16* Vb = VT + (size_t)(b * 8 + kvh) * 128 * 2048;

  const int ktmax = 2 * qt + 1;
  for (int kt = 0; kt <= ktmax; ++kt) {
    #pragma unroll
    for (int c = 0; c < 4; ++c) {
      const int krow = w * 16 + c * 4 + lhi;
      const int kcol = (l16 * 8) ^ ((krow & 7) << 3);
      gload_lds16(&Kb[(size_t)(kt * 64 + krow) * 128 + kcol], &Ks[w * 16 + c * 4][0]);
      const int vrow = w * 32 + c * 8 + (lane >> 3);
      const int vcol = ((lane & 7) * 8) ^ (((lane >> 3) & 7) << 3);
      gload_lds16(&Vb[(size_t)vrow * 2048 + kt * 64 + vcol], &Vs[w * 32 + c * 8][0]);
    }
    __syncthreads();

    // S = Q K^T : kfr shared across the two 16-row sub-blocks
    f32x4 sacc[2][4] = {};
    #pragma unroll
    for (int ni = 0; ni < 4; ++ni)
      #pragma unroll
      for (int kc = 0; kc < 4; ++kc) {
        const short8 kfr = *(const short8*)&Ks[ni * 16 + l16][(kc * 32 + lhi * 8) ^ swz];
        sacc[0][ni] = __builtin_amdgcn_mfma_f32_16x16x32_bf16(qf[0][kc], kfr, sacc[0][ni], 0, 0, 0);
        sacc[1][ni] = __builtin_amdgcn_mfma_f32_16x16x32_bf16(qf[1][kc], kfr, sacc[1][ni], 0, 0, 0);
      }

    const bool diag = (kt >= 2 * qt);
    #pragma unroll
    for (int q2 = 0; q2 < 2; ++q2) {
      float sv[4][4], alpha[4];
      #pragma unroll
      for (int j = 0; j < 4; ++j) {
        const int rloc = w * 32 + q2 * 16 + lhi * 4 + j;   // row within q-tile
        float mx = -1e30f;
        #pragma unroll
        for (int ni = 0; ni < 4; ++ni) {
          float s = sacc[q2][ni][j] * SC;
          // global col kt*64+ni*16+l16 > global row qt*128+rloc ?
          if (diag && (kt * 64 + ni * 16 + l16 > qt * 128 + rloc)) s = -1e30f;
          sv[ni][j] = s;
          mx = fmaxf(mx, s);
        }
        mx = fmaxf(mx, __shfl_xor(mx, 1, 16));
        mx = fmaxf(mx, __shfl_xor(mx, 2, 16));
        mx = fmaxf(mx, __shfl_xor(mx, 4, 16));
        mx = fmaxf(mx, __shfl_xor(mx, 8, 16));
        const float mnew = fmaxf(m_r[q2][j], mx);
        alpha[j] = __expf(m_r[q2][j] - mnew);
        float rs = 0.f;
        #pragma unroll
        for (int ni = 0; ni < 4; ++ni) {
          const float p = __expf(sv[ni][j] - mnew);
          sv[ni][j] = p;
          rs += p;
        }
        rs += __shfl_xor(rs, 1, 16);
        rs += __shfl_xor(rs, 2, 16);
        rs += __shfl_xor(rs, 4, 16);
        rs += __shfl_xor(rs, 8, 16);
        l_r[q2][j] = l_r[q2][j] * alpha[j] + rs;
        m_r[q2][j] = mnew;
      }
      // P -> LDS (bf16), rows q2*16 + lhi*4+j ; (row&7) == (lhi*4+j)&7
      #pragma unroll
      for (int ni = 0; ni < 4; ++ni)
        #pragma unroll
        for (int j = 0; j < 4; ++j)
          Ps[w][q2 * 16 + lhi * 4 + j]
            [(ni * 16 + l16) ^ (((lhi * 4 + j) & 7) << 3)] = f2bf(sv[ni][j]);
      // rescale running context
      #pragma unroll
      for (int nb = 0; nb < 8; ++nb)
        #pragma unroll
        for (int j = 0; j < 4; ++j)
          cacc[q2][nb][j] *= alpha[j];
    }

    // ctx += P * V : vfr shared across the two sub-blocks
    #pragma unroll
    for (int kc2 = 0; kc2 < 2; ++kc2) {
      const short8 pa0 = *(const short8*)&Ps[w][l16][(kc2 * 32 + lhi * 8) ^ swz];
      const short8 pa1 = *(const short8*)&Ps[w][16 + l16][(kc2 * 32 + lhi * 8) ^ swz];
      #pragma unroll
      for (int nb = 0; nb < 8; ++nb) {
        const short8 vfr = *(const short8*)&Vs[nb * 16 + l16][(kc2 * 32 + lhi * 8) ^ swz];
        cacc[0][nb] = __builtin_amdgcn_mfma_f32_16x16x32_bf16(pa0, vfr, cacc[0][nb], 0, 0, 0);
        cacc[1][nb] = __builtin_amdgcn_mfma_f32_16x16x32_bf16(pa1, vfr, cacc[1][nb], 0, 0, 0);
      }
    }
    __syncthreads();
  }

  // write ctx (B,S,H,D) bf16, normalized
  #pragma unroll
  for (int q2 = 0; q2 < 2; ++q2) {
    const size_t crow = (size_t)(b * 2048 + qt * 128 + w * 32 + q2 * 16);
    #pragma unroll
    for (int nb = 0; nb < 8; ++nb)
      #pragma unroll
      for (int j = 0; j < 4; ++j) {
        const float v = cacc[q2][nb][j] / l_r[q2][j];
        CTX[(crow + lhi * 4 + j) * 6144 + h * 128 + nb * 16 + l16] = f2bf(v);
      }
  }
}

// ---------------------------------------------------------------------------
extern "C" void kernel_launch(void* const* d_in, const int* in_sizes, int n_in,
                              void* d_out, int out_size, void* d_ws, size_t ws_size,
                              hipStream_t stream) {
  const float* x    = (const float*)d_in[0];   // (2,2048,6144)
  const float* wqkv = (const float*)d_in[1];   // (8192,6144)
  const float* wo   = (const float*)d_in[2];   // (6144,6144)
  float* out = (float*)d_out;                  // (2,2048,6144) fp32
  char* ws = (char*)d_ws;

  u16* xb  = (u16*)(ws);                  // x bf16        50,331,648
  u16* wqb = (u16*)(ws + 50331648UL);     // Wqkv bf16    100,663,296
  u16* wob = (u16*)(ws + 150994944UL);    // Wo bf16       75,497,472
  u16* qkv = (u16*)(ws + 226492416UL);    // QKV bf16      67,108,864
  u16* Qb  = (u16*)(ws + 293601280UL);    // Q (B,H,S,D)   50,331,648
  u16* Kb  = (u16*)(ws + 343932928UL);    // K (B,KVH,S,D)  8,388,608
  u16* VTb = (u16*)(ws + 352321536UL);    // V^T            8,388,608
  u16* ctx = (u16*)(ws + 360710144UL);    // ctx bf16      50,331,648

  k_f2bf<<<25165824 / 1024, 256, 0, stream>>>(x, xb);
  k_f2bf<<<50331648 / 1024, 256, 0, stream>>>(wqkv, wqb);
  k_f2bf<<<37748736 / 1024, 256, 0, stream>>>(wo, wob);

  k_gemm256<1><<<dim3(8192 / 256, 4096 / 256), 512, 0, stream>>>(
      xb, wqb, qkv, 4096, 8192, 6144);

  k_rope<<<16777216 / 256, 256, 0, stream>>>(qkv, Qb, Kb);
  k_vtrans<<<512, 256, 0, stream>>>(qkv, VTb);

  k_attn<<<2 * 48 * 16, 256, 0, stream>>>(Qb, Kb, VTb, ctx);

  k_gemm256<0><<<dim3(6144 / 256, 4096 / 256), 512, 0, stream>>>(
      ctx, wob, out, 4096, 6144, 6144);
}

// Round 13
// 1121.586 us; speedup vs baseline: 1.0578x; 1.0578x over previous
//
#include <hip/hip_runtime.h>
#include <stdint.h>
#include <stddef.h>

// ---------------------------------------------------------------------------
// InternLM2 attention block, fused pipeline:
//   f2bf(x,Wqkv,Wo) -> GEMM1(bf16)->QKV -> RoPE split -> V-transpose
//   -> flash attention (causal GQA) -> GEMM3(bf16, fp32 out)
// GEMMs: C = A * B^T with A(M,K), B(N,K) row-major.
// MFMA: v_mfma_f32_16x16x32_bf16. C/D: col=l&15, row=(l>>4)*4+j.
//
// R1: attn LDS XOR-swizzle (both-sides) -> attn 874 -> ~230 us.
// R2: same swizzle on GEMM LDS: conflicts 1.51e8 -> 0, GEMM1 681 -> 500 us.
// R3: 256^2 8-phase GEMM (m201 template): 918 TF, MfmaUtil 40%.
// R4/R7: fetch-reducing mappings: dur worse/null -> GEMM not fetch-paced.
// R5/R6: cross-phase read-ahead: spill (252/256 regs). Structurally closed.
// R8: manual lgkm waits removal: NULL.
// R9: 2 phases/K-tile (4 barriers): 396 us, 1041 TF, MfmaUtil 46%. GEMM
//     LOCKED (MFMA+LDS pipes sum to ~93% of cycles; more overlap needs
//     registers we don't have).
// R11: attn 32 q-rows/wave: VGPR blow-up (qf+cacc+sacc doubled) -> spill,
//     attn 240 -> ~345 us. REVERTED.
// R12: QBLK=128 via 8 waves x 16 rows (per-wave structure identical to R9,
//     VGPR-neutral). KV tiles staged once per 128 q-rows (was twice):
//     KV gload traffic + stage/barrier overhead halve per unit work.
//     Masking in global coords; diag tiles when kt >= 2*qt.
// ---------------------------------------------------------------------------

typedef unsigned short u16;
typedef __attribute__((ext_vector_type(8))) short short8;   // bf16x8 frag
typedef __attribute__((ext_vector_type(4))) float f32x4;    // MFMA acc
typedef __attribute__((ext_vector_type(4))) unsigned short u16x4;

typedef const __attribute__((address_space(1))) void* as1_cvp;
typedef __attribute__((address_space(3))) void* as3_vp;

__device__ __forceinline__ float bf2f(u16 u) {
  union { unsigned int i; float f; } v; v.i = ((unsigned)u) << 16; return v.f;
}
__device__ __forceinline__ u16 f2bf(float f) {
  union { float f; unsigned int i; } v; v.f = f;
  unsigned r = v.i + 0x7FFFu + ((v.i >> 16) & 1u);   // RNE
  return (u16)(r >> 16);
}
__device__ __forceinline__ void gload_lds16(const void* g, void* l) {
  __builtin_amdgcn_global_load_lds((as1_cvp)g, (as3_vp)l, 16, 0, 0);
}

// ---------------- fp32 -> bf16 convert (vectorized) ------------------------
__global__ __launch_bounds__(256) void k_f2bf(const float* __restrict__ in,
                                              u16* __restrict__ out) {
  size_t i = ((size_t)blockIdx.x * 256 + threadIdx.x) * 4;
  f32x4 v = *(const f32x4*)(in + i);
  u16x4 o;
  o[0] = f2bf(v[0]); o[1] = f2bf(v[1]); o[2] = f2bf(v[2]); o[3] = f2bf(v[3]);
  *(u16x4*)(out + i) = o;
}

// ---------------- 256x256 2-phase GEMM  C = A * B^T  (R9, locked) ----------
__device__ __forceinline__ void stage_region(const u16* __restrict__ G,
                                             int K, int kt,
                                             u16 (* __restrict__ XS)[64],
                                             int rmap, int w, int lane) {
  #pragma unroll
  for (int L = 0; L < 2; ++L) {
    const int g = w * 2 + L;
    int rb;
    if (rmap == 0)      rb = g * 8 + (g >> 3) * 64;            // A_lo
    else if (rmap == 1) rb = 64 + g * 8 + (g >> 3) * 64;       // A_hi
    else if (rmap == 2) rb = (g >> 2) * 64 + (g & 3) * 8;      // B_lo
    else                rb = 32 + (g >> 2) * 64 + (g & 3) * 8; // B_hi
    const int srow = rb + (lane >> 3);
    const int schunk = ((lane & 7) ^ ((lane >> 3) & 7)) * 8;
    gload_lds16(G + (size_t)srow * K + (size_t)kt * 64 + schunk, &XS[rb][0]);
  }
}

#define LDFRAG(XS, row, ks) \
  (*(const short8*)&XS[row][(((ks) * 32) + lhi * 8) ^ swz])

#define MFMA_Q(af, bf, mb, nb)                                              \
  _Pragma("unroll") for (int mf = 0; mf < 4; ++mf)                          \
  _Pragma("unroll") for (int nf = 0; nf < 2; ++nf)                          \
  _Pragma("unroll") for (int ks = 0; ks < 2; ++ks)                          \
    acc[(mb) + mf][(nb) + nf] = __builtin_amdgcn_mfma_f32_16x16x32_bf16(    \
        af[mf][ks], bf[nf][ks], acc[(mb) + mf][(nb) + nf], 0, 0, 0);

#define GEMM_HALF(H) {                                                      \
  const int tAhi  = (t + 1 + (H) < nkt) ? (t + 1 + (H)) : (nkt - 1);        \
  const int tNext = (t + 2 + (H) < nkt) ? (t + 2 + (H)) : (nkt - 1);        \
  short8 a0[4][2], a1[4][2], b0[2][2], b1[2][2];                            \
  /* ph1: 16 ds_reads; stage A_hi -> other buf; MFMA a0 x (b0,b1) */        \
  _Pragma("unroll") for (int mf = 0; mf < 4; ++mf) {                        \
    a0[mf][0] = LDFRAG(As[H], wm * 128 + mf * 16 + l16, 0);                 \
    a0[mf][1] = LDFRAG(As[H], wm * 128 + mf * 16 + l16, 1); }               \
  _Pragma("unroll") for (int nf = 0; nf < 2; ++nf) {                        \
    b0[nf][0] = LDFRAG(Bs[H], wn * 64 + nf * 16 + l16, 0);                  \
    b0[nf][1] = LDFRAG(Bs[H], wn * 64 + nf * 16 + l16, 1);                  \
    b1[nf][0] = LDFRAG(Bs[H], wn * 64 + (nf + 2) * 16 + l16, 0);            \
    b1[nf][1] = LDFRAG(Bs[H], wn * 64 + (nf + 2) * 16 + l16, 1); }          \
  stage_region(Ap, K, tAhi, As[1 - (H)], 1, w, lane);                       \
  __builtin_amdgcn_s_barrier();                                             \
  __builtin_amdgcn_s_setprio(1);                                            \
  MFMA_Q(a0, b0, 0, 0);                                                     \
  MFMA_Q(a0, b1, 0, 2);                                                     \
  __builtin_amdgcn_s_setprio(0);                                            \
  __builtin_amdgcn_s_barrier();                                             \
  /* ph2: 8 ds_reads (A_hi frags); stage A_lo,B_lo,B_hi; counted vmcnt */   \
  _Pragma("unroll") for (int mf = 0; mf < 4; ++mf) {                        \
    a1[mf][0] = LDFRAG(As[H], wm * 128 + (mf + 4) * 16 + l16, 0);           \
    a1[mf][1] = LDFRAG(As[H], wm * 128 + (mf + 4) * 16 + l16, 1); }         \
  stage_region(Ap, K, tNext, As[H], 0, w, lane);                            \
  stage_region(Bp, K, tNext, Bs[H], 2, w, lane);                            \
  stage_region(Bp, K, tNext, Bs[H], 3, w, lane);                            \
  asm volatile("s_waitcnt vmcnt(6)" ::: "memory");                          \
  __builtin_amdgcn_s_barrier();                                             \
  __builtin_amdgcn_s_setprio(1);                                            \
  MFMA_Q(a1, b0, 4, 0);                                                     \
  MFMA_Q(a1, b1, 4, 2);                                                     \
  __builtin_amdgcn_s_setprio(0);                                            \
  __builtin_amdgcn_s_barrier();                                             \
}

template<int WRITE_BF16>
__global__ __launch_bounds__(512, 2) void k_gemm256(const u16* __restrict__ A,
                                                    const u16* __restrict__ B,
                                                    void* __restrict__ Cout,
                                                    int M, int N, int K) {
  __shared__ u16 As[2][256][64];   // 64 KB
  __shared__ u16 Bs[2][256][64];   // 64 KB
  (void)M;
  const int tid  = threadIdx.x;
  const int lane = tid & 63;
  const int w    = tid >> 6;       // 0..7
  const int wm   = w >> 2;         // 0..1  (row half)
  const int wn   = w & 3;          // 0..3  (col quarter)
  const int l16  = lane & 15, lhi = lane >> 4;
  const int swz  = (l16 & 7) << 3;

  // R3 XCD swizzle (empirically best of 3 mappings; nwg % 8 == 0)
  const int nbx = gridDim.x;
  int id = blockIdx.y * nbx + blockIdx.x;
  const int cpx = (nbx * gridDim.y) >> 3;
  id = (id & 7) * cpx + (id >> 3);
  const long m0 = (long)(id / nbx) * 256;
  const long n0 = (long)(id % nbx) * 256;

  const u16* Ap = A + (size_t)m0 * K;
  const u16* Bp = B + (size_t)n0 * K;

  f32x4 acc[8][4] = {};
  const int nkt = K >> 6;
  const int niter = nkt >> 1;

  // prologue: tile0 (4 regions) -> buf0; tile1 (A_lo,B_lo,B_hi) -> buf1
  stage_region(Ap, K, 0, As[0], 0, w, lane);
  stage_region(Ap, K, 0, As[0], 1, w, lane);
  stage_region(Bp, K, 0, Bs[0], 2, w, lane);
  stage_region(Bp, K, 0, Bs[0], 3, w, lane);
  stage_region(Ap, K, 1, As[1], 0, w, lane);
  stage_region(Bp, K, 1, Bs[1], 2, w, lane);
  stage_region(Bp, K, 1, Bs[1], 3, w, lane);
  asm volatile("s_waitcnt vmcnt(6)" ::: "memory");   // tile0's 8 ops land
  __builtin_amdgcn_s_barrier();

  for (int i = 0; i < niter; ++i) {
    const int t = 2 * i;
    GEMM_HALF(0)
    GEMM_HALF(1)
  }

  asm volatile("s_waitcnt vmcnt(0)" ::: "memory");   // drain dummy prefetches
  #pragma unroll
  for (int mf = 0; mf < 8; ++mf)
    #pragma unroll
    for (int nf = 0; nf < 4; ++nf)
      #pragma unroll
      for (int j = 0; j < 4; ++j) {
        const size_t row = m0 + wm * 128 + mf * 16 + lhi * 4 + j;
        const size_t col = n0 + wn * 64 + nf * 16 + l16;
        const float v = acc[mf][nf][j];
        if (WRITE_BF16) ((u16*)Cout)[row * N + col] = f2bf(v);
        else            ((float*)Cout)[row * N + col] = v;
      }
}

// ---------------- RoPE + Q/K split -----------------------------------------
__global__ __launch_bounds__(256) void k_rope(const u16* __restrict__ QKV,
                                              u16* __restrict__ Qo,
                                              u16* __restrict__ Ko) {
  const unsigned tid = blockIdx.x * 256 + threadIdx.x;
  const int j    = tid & 63;
  const int slot = (tid >> 6) & 7;
  const int kvh  = (tid >> 9) & 7;
  const int t    = tid >> 12;            // 0..4095
  if (slot == 7) return;
  const int b = t >> 11, s = t & 2047;
  const size_t base = (size_t)t * 8192 + kvh * 1024 + slot * 128;
  const float v0 = bf2f(QKV[base + j]);
  const float v1 = bf2f(QKV[base + j + 64]);
  const float invf = __expf(-(float)j * 0.21586735246819181f);
  const float ang = (float)s * invf;
  float sn, cs;
  __sincosf(ang, &sn, &cs);
  const float o0 = v0 * cs - v1 * sn;
  const float o1 = v1 * cs + v0 * sn;
  if (slot < 6) {
    const int hh = kvh * 6 + slot;
    const size_t o = ((size_t)(b * 48 + hh) * 2048 + s) * 128 + j;
    Qo[o] = f2bf(o0); Qo[o + 64] = f2bf(o1);
  } else {
    const size_t o = ((size_t)(b * 8 + kvh) * 2048 + s) * 128 + j;
    Ko[o] = f2bf(o0); Ko[o + 64] = f2bf(o1);
  }
}

// ---------------- V transpose: QKV slot7 -> VT (B,KVH,D,S) -----------------
__global__ __launch_bounds__(256) void k_vtrans(const u16* __restrict__ QKV,
                                                u16* __restrict__ VT) {
  __shared__ u16 T[64][136];             // +8 pad
  const int bid = blockIdx.x;            // 2*8*32 = 512
  const int st  = bid & 31;
  const int kvh = (bid >> 5) & 7;
  const int b   = bid >> 8;
  const int tid = threadIdx.x;
  const int r   = tid >> 4;
  const int c8  = (tid & 15) * 8;
  const size_t qoff = ((size_t)(b * 2048 + st * 64)) * 8192 + kvh * 1024 + 896;
  #pragma unroll
  for (int p = 0; p < 4; ++p) {
    short8 v = *(const short8*)&QKV[qoff + (size_t)(p * 16 + r) * 8192 + c8];
    *(short8*)&T[p * 16 + r][c8] = v;
  }
  __syncthreads();
  const int dd = tid >> 3;
  const int s8 = (tid & 7) * 8;
  const size_t vbase = ((size_t)(b * 8 + kvh) * 128) * 2048 + st * 64;
  #pragma unroll
  for (int p = 0; p < 4; ++p) {
    const int d = p * 32 + dd;
    short8 o;
    #pragma unroll
    for (int i = 0; i < 8; ++i) o[i] = (short)T[s8 + i][d];
    *(short8*)&VT[vbase + (size_t)d * 2048 + s8] = o;
  }
}

// ---------------- flash attention (causal, GQA) ----------------------------
// R12: QBLK=128 via 8 waves x 16 q-rows (per-wave structure == R9's attn).
// Wave w owns rows w*16..w*16+15 of the 128-row q-tile. KV tile (64 cols)
// staged once per 128 q-rows. Causal: kt in [0, 2*qt+1]; diag kt >= 2*qt.
__global__ __launch_bounds__(512) void k_attn(const u16* __restrict__ Q,
                                              const u16* __restrict__ Kg,
                                              const u16* __restrict__ VT,
                                              u16* __restrict__ CTX) {
  __shared__ u16 Ks[64][128];            // 16 KB (s-major, swizzled)
  __shared__ u16 Vs[128][64];            // 16 KB (d-major = V^T tile, swizzled)
  __shared__ u16 Ps[8][16][64];          // 16 KB, per-wave P (swizzled)
  const int bid = blockIdx.x;
  const int qt  = 15 - (bid / 96);       // LPT order, 16 q-tiles of 128 rows
  const int bh  = bid % 96;
  const int h   = bh % 48;
  const int b   = bh / 48;
  const int kvh = h / 6;
  const int tid = threadIdx.x, lane = tid & 63, w = tid >> 6;  // w 0..7
  const int l16 = lane & 15, lhi = lane >> 4;
  const int swz = (l16 & 7) << 3;
  const float SC = 0.08838834764831845f; // 1/sqrt(128)

  short8 qf[4];
  {
    const size_t qrow =
        ((size_t)(b * 48 + h) * 2048 + qt * 128 + w * 16 + l16) * 128;
    #pragma unroll
    for (int kc = 0; kc < 4; ++kc)
      qf[kc] = *(const short8*)&Q[qrow + kc * 32 + lhi * 8];
  }
  f32x4 cacc[8] = {};
  float m_r[4], l_r[4];
  #pragma unroll
  for (int j = 0; j < 4; ++j) { m_r[j] = -1e30f; l_r[j] = 0.f; }

  const u16* Kb = Kg + (size_t)(b * 8 + kvh) * 2048 * 128;
  const u16* Vb = VT + (size_t)(b * 8 + kvh) * 128 * 2048;

  const int ktmax = 2 * qt + 1;
  for (int kt = 0; kt <= ktmax; ++kt) {
    // 32 gloads split over 8 waves: each wave 2 K-chunks + 2 V-chunks
    #pragma unroll
    for (int c = 0; c < 2; ++c) {
      const int kch = w * 2 + c;                      // 0..15
      const int krow = kch * 4 + lhi;
      const int kcol = (l16 * 8) ^ ((krow & 7) << 3);
      gload_lds16(&Kb[(size_t)(kt * 64 + krow) * 128 + kcol], &Ks[kch * 4][0]);
      const int vrow = kch * 8 + (lane >> 3);
      const int vcol = ((lane & 7) * 8) ^ (((lane >> 3) & 7) << 3);
      gload_lds16(&Vb[(size_t)vrow * 2048 + kt * 64 + vcol], &Vs[kch * 8][0]);
    }
    __syncthreads();

    f32x4 sacc[4] = {};
    #pragma unroll
    for (int ni = 0; ni < 4; ++ni)
      #pragma unroll
      for (int kc = 0; kc < 4; ++kc) {
        const short8 kfr = *(const short8*)&Ks[ni * 16 + l16][(kc * 32 + lhi * 8) ^ swz];
        sacc[ni] = __builtin_amdgcn_mfma_f32_16x16x32_bf16(qf[kc], kfr, sacc[ni], 0, 0, 0);
      }

    const bool diag = (kt >= 2 * qt);
    float sv[4][4], alpha[4];
    #pragma unroll
    for (int j = 0; j < 4; ++j) {
      const int grow = qt * 128 + w * 16 + lhi * 4 + j;  // global q row
      float mx = -1e30f;
      #pragma unroll
      for (int ni = 0; ni < 4; ++ni) {
        float s = sacc[ni][j] * SC;
        if (diag && (kt * 64 + ni * 16 + l16 > grow)) s = -1e30f;
        sv[ni][j] = s;
        mx = fmaxf(mx, s);
      }
      mx = fmaxf(mx, __shfl_xor(mx, 1, 16));
      mx = fmaxf(mx, __shfl_xor(mx, 2, 16));
      mx = fmaxf(mx, __shfl_xor(mx, 4, 16));
      mx = fmaxf(mx, __shfl_xor(mx, 8, 16));
      const float mnew = fmaxf(m_r[j], mx);
      alpha[j] = __expf(m_r[j] - mnew);
      float rs = 0.f;
      #pragma unroll
      for (int ni = 0; ni < 4; ++ni) {
        const float p = __expf(sv[ni][j] - mnew);
        sv[ni][j] = p;
        rs += p;
      }
      rs += __shfl_xor(rs, 1, 16);
      rs += __shfl_xor(rs, 2, 16);
      rs += __shfl_xor(rs, 4, 16);
      rs += __shfl_xor(rs, 8, 16);
      l_r[j] = l_r[j] * alpha[j] + rs;
      m_r[j] = mnew;
    }
    #pragma unroll
    for (int ni = 0; ni < 4; ++ni)
      #pragma unroll
      for (int j = 0; j < 4; ++j)
        Ps[w][lhi * 4 + j][(ni * 16 + l16) ^ (((lhi * 4 + j) & 7) << 3)] = f2bf(sv[ni][j]);
    #pragma unroll
    for (int nb = 0; nb < 8; ++nb)
      #pragma unroll
      for (int j = 0; j < 4; ++j)
        cacc[nb][j] *= alpha[j];
    #pragma unroll
    for (int kc2 = 0; kc2 < 2; ++kc2) {
      const short8 pa = *(const short8*)&Ps[w][l16][(kc2 * 32 + lhi * 8) ^ swz];
      #pragma unroll
      for (int nb = 0; nb < 8; ++nb) {
        const short8 vfr = *(const short8*)&Vs[nb * 16 + l16][(kc2 * 32 + lhi * 8) ^ swz];
        cacc[nb] = __builtin_amdgcn_mfma_f32_16x16x32_bf16(pa, vfr, cacc[nb], 0, 0, 0);
      }
    }
    __syncthreads();
  }

  const size_t crow = (size_t)(b * 2048 + qt * 128 + w * 16);
  #pragma unroll
  for (int nb = 0; nb < 8; ++nb)
    #pragma unroll
    for (int j = 0; j < 4; ++j) {
      const float v = cacc[nb][j] / l_r[j];
      CTX[(crow + lhi * 4 + j) * 6144 + h * 128 + nb * 16 + l16] = f2bf(v);
    }
}

// ---------------------------------------------------------------------------
extern "C" void kernel_launch(void* const* d_in, const int* in_sizes, int n_in,
                              void* d_out, int out_size, void* d_ws, size_t ws_size,
                              hipStream_t stream) {
  const float* x    = (const float*)d_in[0];   // (2,2048,6144)
  const float* wqkv = (const float*)d_in[1];   // (8192,6144)
  const float* wo   = (const float*)d_in[2];   // (6144,6144)
  float* out = (float*)d_out;                  // (2,2048,6144) fp32
  char* ws = (char*)d_ws;

  u16* xb  = (u16*)(ws);                  // x bf16        50,331,648
  u16* wqb = (u16*)(ws + 50331648UL);     // Wqkv bf16    100,663,296
  u16* wob = (u16*)(ws + 150994944UL);    // Wo bf16       75,497,472
  u16* qkv = (u16*)(ws + 226492416UL);    // QKV bf16      67,108,864
  u16* Qb  = (u16*)(ws + 293601280UL);    // Q (B,H,S,D)   50,331,648
  u16* Kb  = (u16*)(ws + 343932928UL);    // K (B,KVH,S,D)  8,388,608
  u16* VTb = (u16*)(ws + 352321536UL);    // V^T            8,388,608
  u16* ctx = (u16*)(ws + 360710144UL);    // ctx bf16      50,331,648

  k_f2bf<<<25165824 / 1024, 256, 0, stream>>>(x, xb);
  k_f2bf<<<50331648 / 1024, 256, 0, stream>>>(wqkv, wqb);
  k_f2bf<<<37748736 / 1024, 256, 0, stream>>>(wo, wob);

  k_gemm256<1><<<dim3(8192 / 256, 4096 / 256), 512, 0, stream>>>(
      xb, wqb, qkv, 4096, 8192, 6144);

  k_rope<<<16777216 / 256, 256, 0, stream>>>(qkv, Qb, Kb);
  k_vtrans<<<512, 256, 0, stream>>>(qkv, VTb);

  k_attn<<<2 * 48 * 16, 512, 0, stream>>>(Qb, Kb, VTb, ctx);

  k_gemm256<0><<<dim3(6144 / 256, 4096 / 256), 512, 0, stream>>>(
      ctx, wob, out, 4096, 6144, 6144);
}

// Round 14
// 1079.664 us; speedup vs baseline: 1.0988x; 1.0388x over previous
//
#include <hip/hip_runtime.h>
#include <stdint.h>
#include <stddef.h>

// ---------------------------------------------------------------------------
// InternLM2 attention block, fused pipeline:
//   f2bf(x,Wqkv,Wo) -> GEMM1(bf16)->QKV -> RoPE split -> V-transpose
//   -> flash attention (causal GQA) -> GEMM3(bf16, fp32 out)
// GEMMs: C = A * B^T with A(M,K), B(N,K) row-major.
// MFMA: v_mfma_f32_16x16x32_bf16. C/D: col=l&15, row=(l>>4)*4+j.
//
// R1: attn LDS XOR-swizzle (both-sides) -> attn 874 -> ~230 us.
// R2: same swizzle on GEMM LDS: conflicts 1.51e8 -> 0, GEMM1 681 -> 500 us.
// R3: 256^2 8-phase GEMM (m201 template): 918 TF, MfmaUtil 40%.
// R4/R7: fetch-reducing mappings: dur worse/null -> GEMM not fetch-paced.
// R5/R6: cross-phase read-ahead: spill (252/256 regs). Structurally closed.
// R8: manual lgkm waits removal: NULL.
// R9: 2 phases/K-tile (4 barriers): 396 us, 1041 TF, MfmaUtil 46%. GEMM
//     LOCKED. Total 1080 us = session best.
// R11: attn 32 q-rows/wave: VGPR spill, attn +105 us. REVERTED.
// R12: attn QBLK=128 via 8 waves: blocks/CU 4->2, lost cross-block
//     co-scheduling, attn +42 us. REVERTED.
// R13: restore exact R9 ensemble (best known state). Remaining levers all
//     falsified or structurally closed (register budget / bank-conflict
//     arithmetic / BW-bound converts); re-anchor at 1080.
// ---------------------------------------------------------------------------

typedef unsigned short u16;
typedef __attribute__((ext_vector_type(8))) short short8;   // bf16x8 frag
typedef __attribute__((ext_vector_type(4))) float f32x4;    // MFMA acc
typedef __attribute__((ext_vector_type(4))) unsigned short u16x4;

typedef const __attribute__((address_space(1))) void* as1_cvp;
typedef __attribute__((address_space(3))) void* as3_vp;

__device__ __forceinline__ float bf2f(u16 u) {
  union { unsigned int i; float f; } v; v.i = ((unsigned)u) << 16; return v.f;
}
__device__ __forceinline__ u16 f2bf(float f) {
  union { float f; unsigned int i; } v; v.f = f;
  unsigned r = v.i + 0x7FFFu + ((v.i >> 16) & 1u);   // RNE
  return (u16)(r >> 16);
}
__device__ __forceinline__ void gload_lds16(const void* g, void* l) {
  __builtin_amdgcn_global_load_lds((as1_cvp)g, (as3_vp)l, 16, 0, 0);
}

// ---------------- fp32 -> bf16 convert (vectorized) ------------------------
__global__ __launch_bounds__(256) void k_f2bf(const float* __restrict__ in,
                                              u16* __restrict__ out) {
  size_t i = ((size_t)blockIdx.x * 256 + threadIdx.x) * 4;
  f32x4 v = *(const f32x4*)(in + i);
  u16x4 o;
  o[0] = f2bf(v[0]); o[1] = f2bf(v[1]); o[2] = f2bf(v[2]); o[3] = f2bf(v[3]);
  *(u16x4*)(out + i) = o;
}

// ---------------- 256x256 2-phase GEMM  C = A * B^T  (R9, locked) ----------
__device__ __forceinline__ void stage_region(const u16* __restrict__ G,
                                             int K, int kt,
                                             u16 (* __restrict__ XS)[64],
                                             int rmap, int w, int lane) {
  #pragma unroll
  for (int L = 0; L < 2; ++L) {
    const int g = w * 2 + L;
    int rb;
    if (rmap == 0)      rb = g * 8 + (g >> 3) * 64;            // A_lo
    else if (rmap == 1) rb = 64 + g * 8 + (g >> 3) * 64;       // A_hi
    else if (rmap == 2) rb = (g >> 2) * 64 + (g & 3) * 8;      // B_lo
    else                rb = 32 + (g >> 2) * 64 + (g & 3) * 8; // B_hi
    const int srow = rb + (lane >> 3);
    const int schunk = ((lane & 7) ^ ((lane >> 3) & 7)) * 8;
    gload_lds16(G + (size_t)srow * K + (size_t)kt * 64 + schunk, &XS[rb][0]);
  }
}

#define LDFRAG(XS, row, ks) \
  (*(const short8*)&XS[row][(((ks) * 32) + lhi * 8) ^ swz])

#define MFMA_Q(af, bf, mb, nb)                                              \
  _Pragma("unroll") for (int mf = 0; mf < 4; ++mf)                          \
  _Pragma("unroll") for (int nf = 0; nf < 2; ++nf)                          \
  _Pragma("unroll") for (int ks = 0; ks < 2; ++ks)                          \
    acc[(mb) + mf][(nb) + nf] = __builtin_amdgcn_mfma_f32_16x16x32_bf16(    \
        af[mf][ks], bf[nf][ks], acc[(mb) + mf][(nb) + nf], 0, 0, 0);

#define GEMM_HALF(H) {                                                      \
  const int tAhi  = (t + 1 + (H) < nkt) ? (t + 1 + (H)) : (nkt - 1);        \
  const int tNext = (t + 2 + (H) < nkt) ? (t + 2 + (H)) : (nkt - 1);        \
  short8 a0[4][2], a1[4][2], b0[2][2], b1[2][2];                            \
  /* ph1: 16 ds_reads; stage A_hi -> other buf; MFMA a0 x (b0,b1) */        \
  _Pragma("unroll") for (int mf = 0; mf < 4; ++mf) {                        \
    a0[mf][0] = LDFRAG(As[H], wm * 128 + mf * 16 + l16, 0);                 \
    a0[mf][1] = LDFRAG(As[H], wm * 128 + mf * 16 + l16, 1); }               \
  _Pragma("unroll") for (int nf = 0; nf < 2; ++nf) {                        \
    b0[nf][0] = LDFRAG(Bs[H], wn * 64 + nf * 16 + l16, 0);                  \
    b0[nf][1] = LDFRAG(Bs[H], wn * 64 + nf * 16 + l16, 1);                  \
    b1[nf][0] = LDFRAG(Bs[H], wn * 64 + (nf + 2) * 16 + l16, 0);            \
    b1[nf][1] = LDFRAG(Bs[H], wn * 64 + (nf + 2) * 16 + l16, 1); }          \
  stage_region(Ap, K, tAhi, As[1 - (H)], 1, w, lane);                       \
  __builtin_amdgcn_s_barrier();                                             \
  __builtin_amdgcn_s_setprio(1);                                            \
  MFMA_Q(a0, b0, 0, 0);                                                     \
  MFMA_Q(a0, b1, 0, 2);                                                     \
  __builtin_amdgcn_s_setprio(0);                                            \
  __builtin_amdgcn_s_barrier();                                             \
  /* ph2: 8 ds_reads (A_hi frags); stage A_lo,B_lo,B_hi; counted vmcnt */   \
  _Pragma("unroll") for (int mf = 0; mf < 4; ++mf) {                        \
    a1[mf][0] = LDFRAG(As[H], wm * 128 + (mf + 4) * 16 + l16, 0);           \
    a1[mf][1] = LDFRAG(As[H], wm * 128 + (mf + 4) * 16 + l16, 1); }         \
  stage_region(Ap, K, tNext, As[H], 0, w, lane);                            \
  stage_region(Bp, K, tNext, Bs[H], 2, w, lane);                            \
  stage_region(Bp, K, tNext, Bs[H], 3, w, lane);                            \
  asm volatile("s_waitcnt vmcnt(6)" ::: "memory");                          \
  __builtin_amdgcn_s_barrier();                                             \
  __builtin_amdgcn_s_setprio(1);                                            \
  MFMA_Q(a1, b0, 4, 0);                                                     \
  MFMA_Q(a1, b1, 4, 2);                                                     \
  __builtin_amdgcn_s_setprio(0);                                            \
  __builtin_amdgcn_s_barrier();                                             \
}

template<int WRITE_BF16>
__global__ __launch_bounds__(512, 2) void k_gemm256(const u16* __restrict__ A,
                                                    const u16* __restrict__ B,
                                                    void* __restrict__ Cout,
                                                    int M, int N, int K) {
  __shared__ u16 As[2][256][64];   // 64 KB
  __shared__ u16 Bs[2][256][64];   // 64 KB
  (void)M;
  const int tid  = threadIdx.x;
  const int lane = tid & 63;
  const int w    = tid >> 6;       // 0..7
  const int wm   = w >> 2;         // 0..1  (row half)
  const int wn   = w & 3;          // 0..3  (col quarter)
  const int l16  = lane & 15, lhi = lane >> 4;
  const int swz  = (l16 & 7) << 3;

  // R3 XCD swizzle (empirically best of 3 mappings; nwg % 8 == 0)
  const int nbx = gridDim.x;
  int id = blockIdx.y * nbx + blockIdx.x;
  const int cpx = (nbx * gridDim.y) >> 3;
  id = (id & 7) * cpx + (id >> 3);
  const long m0 = (long)(id / nbx) * 256;
  const long n0 = (long)(id % nbx) * 256;

  const u16* Ap = A + (size_t)m0 * K;
  const u16* Bp = B + (size_t)n0 * K;

  f32x4 acc[8][4] = {};
  const int nkt = K >> 6;
  const int niter = nkt >> 1;

  // prologue: tile0 (4 regions) -> buf0; tile1 (A_lo,B_lo,B_hi) -> buf1
  stage_region(Ap, K, 0, As[0], 0, w, lane);
  stage_region(Ap, K, 0, As[0], 1, w, lane);
  stage_region(Bp, K, 0, Bs[0], 2, w, lane);
  stage_region(Bp, K, 0, Bs[0], 3, w, lane);
  stage_region(Ap, K, 1, As[1], 0, w, lane);
  stage_region(Bp, K, 1, Bs[1], 2, w, lane);
  stage_region(Bp, K, 1, Bs[1], 3, w, lane);
  asm volatile("s_waitcnt vmcnt(6)" ::: "memory");   // tile0's 8 ops land
  __builtin_amdgcn_s_barrier();

  for (int i = 0; i < niter; ++i) {
    const int t = 2 * i;
    GEMM_HALF(0)
    GEMM_HALF(1)
  }

  asm volatile("s_waitcnt vmcnt(0)" ::: "memory");   // drain dummy prefetches
  #pragma unroll
  for (int mf = 0; mf < 8; ++mf)
    #pragma unroll
    for (int nf = 0; nf < 4; ++nf)
      #pragma unroll
      for (int j = 0; j < 4; ++j) {
        const size_t row = m0 + wm * 128 + mf * 16 + lhi * 4 + j;
        const size_t col = n0 + wn * 64 + nf * 16 + l16;
        const float v = acc[mf][nf][j];
        if (WRITE_BF16) ((u16*)Cout)[row * N + col] = f2bf(v);
        else            ((float*)Cout)[row * N + col] = v;
      }
}

// ---------------- RoPE + Q/K split -----------------------------------------
__global__ __launch_bounds__(256) void k_rope(const u16* __restrict__ QKV,
                                              u16* __restrict__ Qo,
                                              u16* __restrict__ Ko) {
  const unsigned tid = blockIdx.x * 256 + threadIdx.x;
  const int j    = tid & 63;
  const int slot = (tid >> 6) & 7;
  const int kvh  = (tid >> 9) & 7;
  const int t    = tid >> 12;            // 0..4095
  if (slot == 7) return;
  const int b = t >> 11, s = t & 2047;
  const size_t base = (size_t)t * 8192 + kvh * 1024 + slot * 128;
  const float v0 = bf2f(QKV[base + j]);
  const float v1 = bf2f(QKV[base + j + 64]);
  const float invf = __expf(-(float)j * 0.21586735246819181f);
  const float ang = (float)s * invf;
  float sn, cs;
  __sincosf(ang, &sn, &cs);
  const float o0 = v0 * cs - v1 * sn;
  const float o1 = v1 * cs + v0 * sn;
  if (slot < 6) {
    const int hh = kvh * 6 + slot;
    const size_t o = ((size_t)(b * 48 + hh) * 2048 + s) * 128 + j;
    Qo[o] = f2bf(o0); Qo[o + 64] = f2bf(o1);
  } else {
    const size_t o = ((size_t)(b * 8 + kvh) * 2048 + s) * 128 + j;
    Ko[o] = f2bf(o0); Ko[o + 64] = f2bf(o1);
  }
}

// ---------------- V transpose: QKV slot7 -> VT (B,KVH,D,S) -----------------
__global__ __launch_bounds__(256) void k_vtrans(const u16* __restrict__ QKV,
                                                u16* __restrict__ VT) {
  __shared__ u16 T[64][136];             // +8 pad
  const int bid = blockIdx.x;            // 2*8*32 = 512
  const int st  = bid & 31;
  const int kvh = (bid >> 5) & 7;
  const int b   = bid >> 8;
  const int tid = threadIdx.x;
  const int r   = tid >> 4;
  const int c8  = (tid & 15) * 8;
  const size_t qoff = ((size_t)(b * 2048 + st * 64)) * 8192 + kvh * 1024 + 896;
  #pragma unroll
  for (int p = 0; p < 4; ++p) {
    short8 v = *(const short8*)&QKV[qoff + (size_t)(p * 16 + r) * 8192 + c8];
    *(short8*)&T[p * 16 + r][c8] = v;
  }
  __syncthreads();
  const int dd = tid >> 3;
  const int s8 = (tid & 7) * 8;
  const size_t vbase = ((size_t)(b * 8 + kvh) * 128) * 2048 + st * 64;
  #pragma unroll
  for (int p = 0; p < 4; ++p) {
    const int d = p * 32 + dd;
    short8 o;
    #pragma unroll
    for (int i = 0; i < 8; ++i) o[i] = (short)T[s8 + i][d];
    *(short8*)&VT[vbase + (size_t)d * 2048 + s8] = o;
  }
}

// ---------------- flash attention (causal, GQA) ----------------------------
// R9 attn (empirical optimum): QBLK=64, 4 waves x 16 q-rows, KVBLK=64.
__global__ __launch_bounds__(256) void k_attn(const u16* __restrict__ Q,
                                              const u16* __restrict__ Kg,
                                              const u16* __restrict__ VT,
                                              u16* __restrict__ CTX) {
  __shared__ u16 Ks[64][128];            // 16 KB (s-major, swizzled)
  __shared__ u16 Vs[128][64];            // 16 KB (d-major = V^T tile, swizzled)
  __shared__ u16 Ps[4][16][64];          // 8 KB, per-wave P (swizzled)
  const int bid = blockIdx.x;
  const int qt  = 31 - (bid / 96);       // LPT order
  const int bh  = bid % 96;
  const int h   = bh % 48;
  const int b   = bh / 48;
  const int kvh = h / 6;
  const int tid = threadIdx.x, lane = tid & 63, w = tid >> 6;
  const int l16 = lane & 15, lhi = lane >> 4;
  const int swz = (l16 & 7) << 3;
  const float SC = 0.08838834764831845f; // 1/sqrt(128)

  short8 qf[4];
  {
    const size_t qrow = ((size_t)(b * 48 + h) * 2048 + qt * 64 + w * 16 + l16) * 128;
    #pragma unroll
    for (int kc = 0; kc < 4; ++kc)
      qf[kc] = *(const short8*)&Q[qrow + kc * 32 + lhi * 8];
  }
  f32x4 cacc[8] = {};
  float m_r[4], l_r[4];
  #pragma unroll
  for (int j = 0; j < 4; ++j) { m_r[j] = -1e30f; l_r[j] = 0.f; }

  const u16* Kb = Kg + (size_t)(b * 8 + kvh) * 2048 * 128;
  const u16* Vb = VT + (size_t)(b * 8 + kvh) * 128 * 2048;

  for (int kt = 0; kt <= qt; ++kt) {
    #pragma unroll
    for (int c = 0; c < 4; ++c) {
      const int krow = w * 16 + c * 4 + lhi;
      const int kcol = (l16 * 8) ^ ((krow & 7) << 3);
      gload_lds16(&Kb[(size_t)(kt * 64 + krow) * 128 + kcol], &Ks[w * 16 + c * 4][0]);
      const int vrow = w * 32 + c * 8 + (lane >> 3);
      const int vcol = ((lane & 7) * 8) ^ (((lane >> 3) & 7) << 3);
      gload_lds16(&Vb[(size_t)vrow * 2048 + kt * 64 + vcol], &Vs[w * 32 + c * 8][0]);
    }
    __syncthreads();

    f32x4 sacc[4] = {};
    #pragma unroll
    for (int ni = 0; ni < 4; ++ni)
      #pragma unroll
      for (int kc = 0; kc < 4; ++kc) {
        const short8 kfr = *(const short8*)&Ks[ni * 16 + l16][(kc * 32 + lhi * 8) ^ swz];
        sacc[ni] = __builtin_amdgcn_mfma_f32_16x16x32_bf16(qf[kc], kfr, sacc[ni], 0, 0, 0);
      }

    const bool diag = (kt == qt);
    float sv[4][4], alpha[4];
    #pragma unroll
    for (int j = 0; j < 4; ++j) {
      const int rloc = w * 16 + lhi * 4 + j;
      float mx = -1e30f;
      #pragma unroll
      for (int ni = 0; ni < 4; ++ni) {
        float s = sacc[ni][j] * SC;
        if (diag && (ni * 16 + l16 > rloc)) s = -1e30f;
        sv[ni][j] = s;
        mx = fmaxf(mx, s);
      }
      mx = fmaxf(mx, __shfl_xor(mx, 1, 16));
      mx = fmaxf(mx, __shfl_xor(mx, 2, 16));
      mx = fmaxf(mx, __shfl_xor(mx, 4, 16));
      mx = fmaxf(mx, __shfl_xor(mx, 8, 16));
      const float mnew = fmaxf(m_r[j], mx);
      alpha[j] = __expf(m_r[j] - mnew);
      float rs = 0.f;
      #pragma unroll
      for (int ni = 0; ni < 4; ++ni) {
        const float p = __expf(sv[ni][j] - mnew);
        sv[ni][j] = p;
        rs += p;
      }
      rs += __shfl_xor(rs, 1, 16);
      rs += __shfl_xor(rs, 2, 16);
      rs += __shfl_xor(rs, 4, 16);
      rs += __shfl_xor(rs, 8, 16);
      l_r[j] = l_r[j] * alpha[j] + rs;
      m_r[j] = mnew;
    }
    #pragma unroll
    for (int ni = 0; ni < 4; ++ni)
      #pragma unroll
      for (int j = 0; j < 4; ++j)
        Ps[w][lhi * 4 + j][(ni * 16 + l16) ^ (((lhi * 4 + j) & 7) << 3)] = f2bf(sv[ni][j]);
    #pragma unroll
    for (int nb = 0; nb < 8; ++nb)
      #pragma unroll
      for (int j = 0; j < 4; ++j)
        cacc[nb][j] *= alpha[j];
    #pragma unroll
    for (int kc2 = 0; kc2 < 2; ++kc2) {
      const short8 pa = *(const short8*)&Ps[w][l16][(kc2 * 32 + lhi * 8) ^ swz];
      #pragma unroll
      for (int nb = 0; nb < 8; ++nb) {
        const short8 vfr = *(const short8*)&Vs[nb * 16 + l16][(kc2 * 32 + lhi * 8) ^ swz];
        cacc[nb] = __builtin_amdgcn_mfma_f32_16x16x32_bf16(pa, vfr, cacc[nb], 0, 0, 0);
      }
    }
    __syncthreads();
  }

  const size_t crow = (size_t)(b * 2048 + qt * 64 + w * 16);
  #pragma unroll
  for (int nb = 0; nb < 8; ++nb)
    #pragma unroll
    for (int j = 0; j < 4; ++j) {
      const float v = cacc[nb][j] / l_r[j];
      CTX[(crow + lhi * 4 + j) * 6144 + h * 128 + nb * 16 + l16] = f2bf(v);
    }
}

// ---------------------------------------------------------------------------
extern "C" void kernel_launch(void* const* d_in, const int* in_sizes, int n_in,
                              void* d_out, int out_size, void* d_ws, size_t ws_size,
                              hipStream_t stream) {
  const float* x    = (const float*)d_in[0];   // (2,2048,6144)
  const float* wqkv = (const float*)d_in[1];   // (8192,6144)
  const float* wo   = (const float*)d_in[2];   // (6144,6144)
  float* out = (float*)d_out;                  // (2,2048,6144) fp32
  char* ws = (char*)d_ws;

  u16* xb  = (u16*)(ws);                  // x bf16        50,331,648
  u16* wqb = (u16*)(ws + 50331648UL);     // Wqkv bf16    100,663,296
  u16* wob = (u16*)(ws + 150994944UL);    // Wo bf16       75,497,472
  u16* qkv = (u16*)(ws + 226492416UL);    // QKV bf16      67,108,864
  u16* Qb  = (u16*)(ws + 293601280UL);    // Q (B,H,S,D)   50,331,648
  u16* Kb  = (u16*)(ws + 343932928UL);    // K (B,KVH,S,D)  8,388,608
  u16* VTb = (u16*)(ws + 352321536UL);    // V^T            8,388,608
  u16* ctx = (u16*)(ws + 360710144UL);    // ctx bf16      50,331,648

  k_f2bf<<<25165824 / 1024, 256, 0, stream>>>(x, xb);
  k_f2bf<<<50331648 / 1024, 256, 0, stream>>>(wqkv, wqb);
  k_f2bf<<<37748736 / 1024, 256, 0, stream>>>(wo, wob);

  k_gemm256<1><<<dim3(8192 / 256, 4096 / 256), 512, 0, stream>>>(
      xb, wqb, qkv, 4096, 8192, 6144);

  k_rope<<<16777216 / 256, 256, 0, stream>>>(qkv, Qb, Kb);
  k_vtrans<<<512, 256, 0, stream>>>(qkv, VTb);

  k_attn<<<2 * 48 * 32, 256, 0, stream>>>(Qb, Kb, VTb, ctx);

  k_gemm256<0><<<dim3(6144 / 256, 4096 / 256), 512, 0, stream>>>(
      ctx, wob, out, 4096, 6144, 6144);
}

// Round 15
// 1067.065 us; speedup vs baseline: 1.1118x; 1.0118x over previous
//
#include <hip/hip_runtime.h>
#include <stdint.h>
#include <stddef.h>

// ---------------------------------------------------------------------------
// InternLM2 attention block, fused pipeline:
//   f2bf(x,Wqkv,Wo) -> GEMM1(bf16)->QKV -> RoPE split -> V-transpose
//   -> flash attention (causal GQA) -> GEMM3(bf16, fp32 out)
// GEMMs: C = A * B^T with A(M,K), B(N,K) row-major.
// MFMA: v_mfma_f32_16x16x32_bf16. C/D: col=l&15, row=(l>>4)*4+j.
//
// R1: attn LDS XOR-swizzle (both-sides) -> attn 874 -> ~230 us.
// R2: same swizzle on GEMM LDS: conflicts 1.51e8 -> 0, GEMM1 681 -> 500 us.
// R3: 256^2 8-phase GEMM (m201 template): 918 TF, MfmaUtil 40%.
// R4/R7: fetch-reducing mappings: dur worse/null -> GEMM not fetch-paced.
// R5/R6: cross-phase read-ahead: spill (252/256 regs). Structurally closed.
// R8: manual lgkm waits removal: NULL.
// R9: 2 phases/K-tile (4 barriers): 396 us, 1041 TF, MfmaUtil 46%. GEMM
//     LOCKED (per-K-tile 4950 cyc = MFMA 2483 + LDS 2304 serial; overlap
//     needs frag regs past the 256 unified cliff; 1-phase variant derived
//     to spill: 96 frag + 128 acc + addr > 256).
// R11: attn 32 q-rows/wave: VGPR spill. REVERTED.
// R12: attn QBLK=128 via 8 waves: occupancy 4->2 blocks/CU. REVERTED.
// R13: restored R9 ensemble: 1080 us anchor reproduced.
// R14: (a) T13 defer-max in attn: skip alpha-rescale when max growth <= 8
//     (wave-uniform __any branch; alpha[] removed from live set, max
//     recomputed in the rare branch -> register-neutral at the 128-VGPR
//     cliff). (b) merge 3 f2bf launches into one range-dispatched kernel.
// ---------------------------------------------------------------------------

typedef unsigned short u16;
typedef __attribute__((ext_vector_type(8))) short short8;   // bf16x8 frag
typedef __attribute__((ext_vector_type(4))) float f32x4;    // MFMA acc
typedef __attribute__((ext_vector_type(4))) unsigned short u16x4;

typedef const __attribute__((address_space(1))) void* as1_cvp;
typedef __attribute__((address_space(3))) void* as3_vp;

__device__ __forceinline__ float bf2f(u16 u) {
  union { unsigned int i; float f; } v; v.i = ((unsigned)u) << 16; return v.f;
}
__device__ __forceinline__ u16 f2bf(float f) {
  union { float f; unsigned int i; } v; v.f = f;
  unsigned r = v.i + 0x7FFFu + ((v.i >> 16) & 1u);   // RNE
  return (u16)(r >> 16);
}
__device__ __forceinline__ void gload_lds16(const void* g, void* l) {
  __builtin_amdgcn_global_load_lds((as1_cvp)g, (as3_vp)l, 16, 0, 0);
}

// ---------------- fp32 -> bf16 convert (fused 3-buffer, vectorized) --------
// block ranges: [0,24576) x ; [24576,73728) wqkv ; [73728,110592) wo
__global__ __launch_bounds__(256) void k_f2bf3(const float* __restrict__ xi,
                                               const float* __restrict__ wqi,
                                               const float* __restrict__ woi,
                                               u16* __restrict__ xo,
                                               u16* __restrict__ wqo,
                                               u16* __restrict__ woo) {
  int bid = blockIdx.x;
  const float* in; u16* out;
  if (bid < 24576)      { in = xi;  out = xo; }
  else if (bid < 73728) { in = wqi; out = wqo; bid -= 24576; }
  else                  { in = woi; out = woo; bid -= 73728; }
  const size_t i = ((size_t)bid * 256 + threadIdx.x) * 4;
  f32x4 v = *(const f32x4*)(in + i);
  u16x4 o;
  o[0] = f2bf(v[0]); o[1] = f2bf(v[1]); o[2] = f2bf(v[2]); o[3] = f2bf(v[3]);
  *(u16x4*)(out + i) = o;
}

// ---------------- 256x256 2-phase GEMM  C = A * B^T  (R9, locked) ----------
__device__ __forceinline__ void stage_region(const u16* __restrict__ G,
                                             int K, int kt,
                                             u16 (* __restrict__ XS)[64],
                                             int rmap, int w, int lane) {
  #pragma unroll
  for (int L = 0; L < 2; ++L) {
    const int g = w * 2 + L;
    int rb;
    if (rmap == 0)      rb = g * 8 + (g >> 3) * 64;            // A_lo
    else if (rmap == 1) rb = 64 + g * 8 + (g >> 3) * 64;       // A_hi
    else if (rmap == 2) rb = (g >> 2) * 64 + (g & 3) * 8;      // B_lo
    else                rb = 32 + (g >> 2) * 64 + (g & 3) * 8; // B_hi
    const int srow = rb + (lane >> 3);
    const int schunk = ((lane & 7) ^ ((lane >> 3) & 7)) * 8;
    gload_lds16(G + (size_t)srow * K + (size_t)kt * 64 + schunk, &XS[rb][0]);
  }
}

#define LDFRAG(XS, row, ks) \
  (*(const short8*)&XS[row][(((ks) * 32) + lhi * 8) ^ swz])

#define MFMA_Q(af, bf, mb, nb)                                              \
  _Pragma("unroll") for (int mf = 0; mf < 4; ++mf)                          \
  _Pragma("unroll") for (int nf = 0; nf < 2; ++nf)                          \
  _Pragma("unroll") for (int ks = 0; ks < 2; ++ks)                          \
    acc[(mb) + mf][(nb) + nf] = __builtin_amdgcn_mfma_f32_16x16x32_bf16(    \
        af[mf][ks], bf[nf][ks], acc[(mb) + mf][(nb) + nf], 0, 0, 0);

#define GEMM_HALF(H) {                                                      \
  const int tAhi  = (t + 1 + (H) < nkt) ? (t + 1 + (H)) : (nkt - 1);        \
  const int tNext = (t + 2 + (H) < nkt) ? (t + 2 + (H)) : (nkt - 1);        \
  short8 a0[4][2], a1[4][2], b0[2][2], b1[2][2];                            \
  /* ph1: 16 ds_reads; stage A_hi -> other buf; MFMA a0 x (b0,b1) */        \
  _Pragma("unroll") for (int mf = 0; mf < 4; ++mf) {                        \
    a0[mf][0] = LDFRAG(As[H], wm * 128 + mf * 16 + l16, 0);                 \
    a0[mf][1] = LDFRAG(As[H], wm * 128 + mf * 16 + l16, 1); }               \
  _Pragma("unroll") for (int nf = 0; nf < 2; ++nf) {                        \
    b0[nf][0] = LDFRAG(Bs[H], wn * 64 + nf * 16 + l16, 0);                  \
    b0[nf][1] = LDFRAG(Bs[H], wn * 64 + nf * 16 + l16, 1);                  \
    b1[nf][0] = LDFRAG(Bs[H], wn * 64 + (nf + 2) * 16 + l16, 0);            \
    b1[nf][1] = LDFRAG(Bs[H], wn * 64 + (nf + 2) * 16 + l16, 1); }          \
  stage_region(Ap, K, tAhi, As[1 - (H)], 1, w, lane);                       \
  __builtin_amdgcn_s_barrier();                                             \
  __builtin_amdgcn_s_setprio(1);                                            \
  MFMA_Q(a0, b0, 0, 0);                                                     \
  MFMA_Q(a0, b1, 0, 2);                                                     \
  __builtin_amdgcn_s_setprio(0);                                            \
  __builtin_amdgcn_s_barrier();                                             \
  /* ph2: 8 ds_reads (A_hi frags); stage A_lo,B_lo,B_hi; counted vmcnt */   \
  _Pragma("unroll") for (int mf = 0; mf < 4; ++mf) {                        \
    a1[mf][0] = LDFRAG(As[H], wm * 128 + (mf + 4) * 16 + l16, 0);           \
    a1[mf][1] = LDFRAG(As[H], wm * 128 + (mf + 4) * 16 + l16, 1); }         \
  stage_region(Ap, K, tNext, As[H], 0, w, lane);                            \
  stage_region(Bp, K, tNext, Bs[H], 2, w, lane);                            \
  stage_region(Bp, K, tNext, Bs[H], 3, w, lane);                            \
  asm volatile("s_waitcnt vmcnt(6)" ::: "memory");                          \
  __builtin_amdgcn_s_barrier();                                             \
  __builtin_amdgcn_s_setprio(1);                                            \
  MFMA_Q(a1, b0, 4, 0);                                                     \
  MFMA_Q(a1, b1, 4, 2);                                                     \
  __builtin_amdgcn_s_setprio(0);                                            \
  __builtin_amdgcn_s_barrier();                                             \
}

template<int WRITE_BF16>
__global__ __launch_bounds__(512, 2) void k_gemm256(const u16* __restrict__ A,
                                                    const u16* __restrict__ B,
                                                    void* __restrict__ Cout,
                                                    int M, int N, int K) {
  __shared__ u16 As[2][256][64];   // 64 KB
  __shared__ u16 Bs[2][256][64];   // 64 KB
  (void)M;
  const int tid  = threadIdx.x;
  const int lane = tid & 63;
  const int w    = tid >> 6;       // 0..7
  const int wm   = w >> 2;         // 0..1  (row half)
  const int wn   = w & 3;          // 0..3  (col quarter)
  const int l16  = lane & 15, lhi = lane >> 4;
  const int swz  = (l16 & 7) << 3;

  // R3 XCD swizzle (empirically best of 3 mappings; nwg % 8 == 0)
  const int nbx = gridDim.x;
  int id = blockIdx.y * nbx + blockIdx.x;
  const int cpx = (nbx * gridDim.y) >> 3;
  id = (id & 7) * cpx + (id >> 3);
  const long m0 = (long)(id / nbx) * 256;
  const long n0 = (long)(id % nbx) * 256;

  const u16* Ap = A + (size_t)m0 * K;
  const u16* Bp = B + (size_t)n0 * K;

  f32x4 acc[8][4] = {};
  const int nkt = K >> 6;
  const int niter = nkt >> 1;

  // prologue: tile0 (4 regions) -> buf0; tile1 (A_lo,B_lo,B_hi) -> buf1
  stage_region(Ap, K, 0, As[0], 0, w, lane);
  stage_region(Ap, K, 0, As[0], 1, w, lane);
  stage_region(Bp, K, 0, Bs[0], 2, w, lane);
  stage_region(Bp, K, 0, Bs[0], 3, w, lane);
  stage_region(Ap, K, 1, As[1], 0, w, lane);
  stage_region(Bp, K, 1, Bs[1], 2, w, lane);
  stage_region(Bp, K, 1, Bs[1], 3, w, lane);
  asm volatile("s_waitcnt vmcnt(6)" ::: "memory");   // tile0's 8 ops land
  __builtin_amdgcn_s_barrier();

  for (int i = 0; i < niter; ++i) {
    const int t = 2 * i;
    GEMM_HALF(0)
    GEMM_HALF(1)
  }

  asm volatile("s_waitcnt vmcnt(0)" ::: "memory");   // drain dummy prefetches
  #pragma unroll
  for (int mf = 0; mf < 8; ++mf)
    #pragma unroll
    for (int nf = 0; nf < 4; ++nf)
      #pragma unroll
      for (int j = 0; j < 4; ++j) {
        const size_t row = m0 + wm * 128 + mf * 16 + lhi * 4 + j;
        const size_t col = n0 + wn * 64 + nf * 16 + l16;
        const float v = acc[mf][nf][j];
        if (WRITE_BF16) ((u16*)Cout)[row * N + col] = f2bf(v);
        else            ((float*)Cout)[row * N + col] = v;
      }
}

// ---------------- RoPE + Q/K split -----------------------------------------
__global__ __launch_bounds__(256) void k_rope(const u16* __restrict__ QKV,
                                              u16* __restrict__ Qo,
                                              u16* __restrict__ Ko) {
  const unsigned tid = blockIdx.x * 256 + threadIdx.x;
  const int j    = tid & 63;
  const int slot = (tid >> 6) & 7;
  const int kvh  = (tid >> 9) & 7;
  const int t    = tid >> 12;            // 0..4095
  if (slot == 7) return;
  const int b = t >> 11, s = t & 2047;
  const size_t base = (size_t)t * 8192 + kvh * 1024 + slot * 128;
  const float v0 = bf2f(QKV[base + j]);
  const float v1 = bf2f(QKV[base + j + 64]);
  const float invf = __expf(-(float)j * 0.21586735246819181f);
  const float ang = (float)s * invf;
  float sn, cs;
  __sincosf(ang, &sn, &cs);
  const float o0 = v0 * cs - v1 * sn;
  const float o1 = v1 * cs + v0 * sn;
  if (slot < 6) {
    const int hh = kvh * 6 + slot;
    const size_t o = ((size_t)(b * 48 + hh) * 2048 + s) * 128 + j;
    Qo[o] = f2bf(o0); Qo[o + 64] = f2bf(o1);
  } else {
    const size_t o = ((size_t)(b * 8 + kvh) * 2048 + s) * 128 + j;
    Ko[o] = f2bf(o0); Ko[o + 64] = f2bf(o1);
  }
}

// ---------------- V transpose: QKV slot7 -> VT (B,KVH,D,S) -----------------
__global__ __launch_bounds__(256) void k_vtrans(const u16* __restrict__ QKV,
                                                u16* __restrict__ VT) {
  __shared__ u16 T[64][136];             // +8 pad
  const int bid = blockIdx.x;            // 2*8*32 = 512
  const int st  = bid & 31;
  const int kvh = (bid >> 5) & 7;
  const int b   = bid >> 8;
  const int tid = threadIdx.x;
  const int r   = tid >> 4;
  const int c8  = (tid & 15) * 8;
  const size_t qoff = ((size_t)(b * 2048 + st * 64)) * 8192 + kvh * 1024 + 896;
  #pragma unroll
  for (int p = 0; p < 4; ++p) {
    short8 v = *(const short8*)&QKV[qoff + (size_t)(p * 16 + r) * 8192 + c8];
    *(short8*)&T[p * 16 + r][c8] = v;
  }
  __syncthreads();
  const int dd = tid >> 3;
  const int s8 = (tid & 7) * 8;
  const size_t vbase = ((size_t)(b * 8 + kvh) * 128) * 2048 + st * 64;
  #pragma unroll
  for (int p = 0; p < 4; ++p) {
    const int d = p * 32 + dd;
    short8 o;
    #pragma unroll
    for (int i = 0; i < 8; ++i) o[i] = (short)T[s8 + i][d];
    *(short8*)&VT[vbase + (size_t)d * 2048 + s8] = o;
  }
}

// ---------------- flash attention (causal, GQA) ----------------------------
// R9 attn + T13 defer-max: QBLK=64, 4 waves x 16 q-rows, KVBLK=64.
// Rescale branch taken only when some row's max grows past m_r + 8;
// otherwise P = exp(s - m_old) <= e^8 (bf16-safe, fp32 l/cacc).
__global__ __launch_bounds__(256) void k_attn(const u16* __restrict__ Q,
                                              const u16* __restrict__ Kg,
                                              const u16* __restrict__ VT,
                                              u16* __restrict__ CTX) {
  __shared__ u16 Ks[64][128];            // 16 KB (s-major, swizzled)
  __shared__ u16 Vs[128][64];            // 16 KB (d-major = V^T tile, swizzled)
  __shared__ u16 Ps[4][16][64];          // 8 KB, per-wave P (swizzled)
  const int bid = blockIdx.x;
  const int qt  = 31 - (bid / 96);       // LPT order
  const int bh  = bid % 96;
  const int h   = bh % 48;
  const int b   = bh / 48;
  const int kvh = h / 6;
  const int tid = threadIdx.x, lane = tid & 63, w = tid >> 6;
  const int l16 = lane & 15, lhi = lane >> 4;
  const int swz = (l16 & 7) << 3;
  const float SC = 0.08838834764831845f; // 1/sqrt(128)

  short8 qf[4];
  {
    const size_t qrow = ((size_t)(b * 48 + h) * 2048 + qt * 64 + w * 16 + l16) * 128;
    #pragma unroll
    for (int kc = 0; kc < 4; ++kc)
      qf[kc] = *(const short8*)&Q[qrow + kc * 32 + lhi * 8];
  }
  f32x4 cacc[8] = {};
  float m_r[4], l_r[4];
  #pragma unroll
  for (int j = 0; j < 4; ++j) { m_r[j] = -1e30f; l_r[j] = 0.f; }

  const u16* Kb = Kg + (size_t)(b * 8 + kvh) * 2048 * 128;
  const u16* Vb = VT + (size_t)(b * 8 + kvh) * 128 * 2048;

  for (int kt = 0; kt <= qt; ++kt) {
    #pragma unroll
    for (int c = 0; c < 4; ++c) {
      const int krow = w * 16 + c * 4 + lhi;
      const int kcol = (l16 * 8) ^ ((krow & 7) << 3);
      gload_lds16(&Kb[(size_t)(kt * 64 + krow) * 128 + kcol], &Ks[w * 16 + c * 4][0]);
      const int vrow = w * 32 + c * 8 + (lane >> 3);
      const int vcol = ((lane & 7) * 8) ^ (((lane >> 3) & 7) << 3);
      gload_lds16(&Vb[(size_t)vrow * 2048 + kt * 64 + vcol], &Vs[w * 32 + c * 8][0]);
    }
    __syncthreads();

    f32x4 sacc[4] = {};
    #pragma unroll
    for (int ni = 0; ni < 4; ++ni)
      #pragma unroll
      for (int kc = 0; kc < 4; ++kc) {
        const short8 kfr = *(const short8*)&Ks[ni * 16 + l16][(kc * 32 + lhi * 8) ^ swz];
        sacc[ni] = __builtin_amdgcn_mfma_f32_16x16x32_bf16(qf[kc], kfr, sacc[ni], 0, 0, 0);
      }

    // pass 1: scale + mask; detect max growth (T13)
    const bool diag = (kt == qt);
    float sv[4][4];
    bool grow = false;
    #pragma unroll
    for (int j = 0; j < 4; ++j) {
      const int rloc = w * 16 + lhi * 4 + j;
      float mx = -1e30f;
      #pragma unroll
      for (int ni = 0; ni < 4; ++ni) {
        float s = sacc[ni][j] * SC;
        if (diag && (ni * 16 + l16 > rloc)) s = -1e30f;
        sv[ni][j] = s;
        mx = fmaxf(mx, s);
      }
      mx = fmaxf(mx, __shfl_xor(mx, 1, 16));
      mx = fmaxf(mx, __shfl_xor(mx, 2, 16));
      mx = fmaxf(mx, __shfl_xor(mx, 4, 16));
      mx = fmaxf(mx, __shfl_xor(mx, 8, 16));
      grow |= (mx > m_r[j] + 8.f);
    }
    // rescale branch (rare after the first tiles): recompute max, rescale
    if (__any(grow)) {
      #pragma unroll
      for (int j = 0; j < 4; ++j) {
        float mx = -1e30f;
        #pragma unroll
        for (int ni = 0; ni < 4; ++ni) mx = fmaxf(mx, sv[ni][j]);
        mx = fmaxf(mx, __shfl_xor(mx, 1, 16));
        mx = fmaxf(mx, __shfl_xor(mx, 2, 16));
        mx = fmaxf(mx, __shfl_xor(mx, 4, 16));
        mx = fmaxf(mx, __shfl_xor(mx, 8, 16));
        const float mnew = fmaxf(m_r[j], mx);
        const float alpha = __expf(m_r[j] - mnew);
        m_r[j] = mnew;
        l_r[j] *= alpha;
        #pragma unroll
        for (int nb = 0; nb < 8; ++nb)
          cacc[nb][j] *= alpha;
      }
    }
    // pass 2: exp against (possibly stale) m_r; accumulate l
    #pragma unroll
    for (int j = 0; j < 4; ++j) {
      float rs = 0.f;
      #pragma unroll
      for (int ni = 0; ni < 4; ++ni) {
        const float p = __expf(sv[ni][j] - m_r[j]);
        sv[ni][j] = p;
        rs += p;
      }
      rs += __shfl_xor(rs, 1, 16);
      rs += __shfl_xor(rs, 2, 16);
      rs += __shfl_xor(rs, 4, 16);
      rs += __shfl_xor(rs, 8, 16);
      l_r[j] += rs;
    }
    #pragma unroll
    for (int ni = 0; ni < 4; ++ni)
      #pragma unroll
      for (int j = 0; j < 4; ++j)
        Ps[w][lhi * 4 + j][(ni * 16 + l16) ^ (((lhi * 4 + j) & 7) << 3)] = f2bf(sv[ni][j]);
    #pragma unroll
    for (int kc2 = 0; kc2 < 2; ++kc2) {
      const short8 pa = *(const short8*)&Ps[w][l16][(kc2 * 32 + lhi * 8) ^ swz];
      #pragma unroll
      for (int nb = 0; nb < 8; ++nb) {
        const short8 vfr = *(const short8*)&Vs[nb * 16 + l16][(kc2 * 32 + lhi * 8) ^ swz];
        cacc[nb] = __builtin_amdgcn_mfma_f32_16x16x32_bf16(pa, vfr, cacc[nb], 0, 0, 0);
      }
    }
    __syncthreads();
  }

  const size_t crow = (size_t)(b * 2048 + qt * 64 + w * 16);
  #pragma unroll
  for (int nb = 0; nb < 8; ++nb)
    #pragma unroll
    for (int j = 0; j < 4; ++j) {
      const float v = cacc[nb][j] / l_r[j];
      CTX[(crow + lhi * 4 + j) * 6144 + h * 128 + nb * 16 + l16] = f2bf(v);
    }
}

// ---------------------------------------------------------------------------
extern "C" void kernel_launch(void* const* d_in, const int* in_sizes, int n_in,
                              void* d_out, int out_size, void* d_ws, size_t ws_size,
                              hipStream_t stream) {
  const float* x    = (const float*)d_in[0];   // (2,2048,6144)
  const float* wqkv = (const float*)d_in[1];   // (8192,6144)
  const float* wo   = (const float*)d_in[2];   // (6144,6144)
  float* out = (float*)d_out;                  // (2,2048,6144) fp32
  char* ws = (char*)d_ws;

  u16* xb  = (u16*)(ws);                  // x bf16        50,331,648
  u16* wqb = (u16*)(ws + 50331648UL);     // Wqkv bf16    100,663,296
  u16* wob = (u16*)(ws + 150994944UL);    // Wo bf16       75,497,472
  u16* qkv = (u16*)(ws + 226492416UL);    // QKV bf16      67,108,864
  u16* Qb  = (u16*)(ws + 293601280UL);    // Q (B,H,S,D)   50,331,648
  u16* Kb  = (u16*)(ws + 343932928UL);    // K (B,KVH,S,D)  8,388,608
  u16* VTb = (u16*)(ws + 352321536UL);    // V^T            8,388,608
  u16* ctx = (u16*)(ws + 360710144UL);    // ctx bf16      50,331,648

  k_f2bf3<<<110592, 256, 0, stream>>>(x, wqkv, wo, xb, wqb, wob);

  k_gemm256<1><<<dim3(8192 / 256, 4096 / 256), 512, 0, stream>>>(
      xb, wqb, qkv, 4096, 8192, 6144);

  k_rope<<<16777216 / 256, 256, 0, stream>>>(qkv, Qb, Kb);
  k_vtrans<<<512, 256, 0, stream>>>(qkv, VTb);

  k_attn<<<2 * 48 * 32, 256, 0, stream>>>(Qb, Kb, VTb, ctx);

  k_gemm256<0><<<dim3(6144 / 256, 4096 / 256), 512, 0, stream>>>(
      ctx, wob, out, 4096, 6144, 6144);
}